// Round 4
// baseline (144.038 us; speedup 1.0000x reference)
//
#include <hip/hip_runtime.h>

#define DD 512
#define MM 64
#define BB 16
#define NN 8192
#define KK 4
#define DP1 513

// ws byte offsets (new compact layout)
#define U_B    0                      // fp16 u[m][d][b], 1 MB
#define UT_B   1048576                // bf16 ut[m][b][d], 1 MB
#define GRAM_B 2097152                // fp32 G[e][f][16][16], 4 MB
#define WS_NEED 6291456

typedef unsigned int uint;
typedef unsigned short ushort;
typedef __attribute__((ext_vector_type(8))) short short8;
typedef __attribute__((ext_vector_type(4))) float f32x4;
typedef __attribute__((ext_vector_type(2))) _Float16 half2v;

__device__ __forceinline__ ushort f2bf(float f) {
    uint u = __builtin_bit_cast(uint, f);
    uint r = (u + 0x7FFFu + ((u >> 16) & 1u)) >> 16;
    return (ushort)r;
}
__device__ __forceinline__ ushort f2h(float f) {
    _Float16 h = (_Float16)f;
    return __builtin_bit_cast(ushort, h);
}

// dot2: c += a.x*b.x + a.y*b.y with fp16 inputs, fp32 accumulate
__device__ __forceinline__ float dot2h(uint a, uint b, float c) {
#if __has_builtin(__builtin_amdgcn_fdot2)
    return __builtin_amdgcn_fdot2(__builtin_bit_cast(half2v, a),
                                  __builtin_bit_cast(half2v, b), c, false);
#else
    half2v av = __builtin_bit_cast(half2v, a);
    half2v bv = __builtin_bit_cast(half2v, b);
    return c + (float)av.x * (float)bv.x + (float)av.y * (float)bv.y;
#endif
}

// ---------------------------------------------------------------------------
// K1 prep2: 256 blocks (4 per expert, d-slice of 128).
// Writes u (fp16, [e][d][b]) and ut (bf16, [e][b][d]); zeroes loss slot.
// No sort, no counters.
// ---------------------------------------------------------------------------
__global__ __launch_bounds__(256) void prep2(
    const float* __restrict__ U,
    void* __restrict__ ws,
    float* __restrict__ loss_slot)
{
    const int blk = blockIdx.x, t = threadIdx.x;
    const int m = blk >> 2, sl = blk & 3;
    const float* Um = U + (long)m * DP1 * BB;

    __shared__ float red[256];
    __shared__ float inv_s[BB];
    __shared__ ushort tr[BB][136];

    float a = 0.f;
    for (int i = t; i < DP1 * BB; i += 256) { float v = Um[i]; a += v * v; }
    red[t] = a;
    __syncthreads();
    if (t < BB) {
        float tot = 0.f;
        #pragma unroll
        for (int j = 0; j < 16; ++j) tot += red[t + 16 * j];
        inv_s[t] = rsqrtf(tot);
    }
    __syncthreads();

    ushort* uh = (ushort*)((char*)ws + U_B) + (long)m * DD * BB + sl * 2048;
    ushort* ut = (ushort*)((char*)ws + UT_B) + (long)m * BB * DD + sl * 128;
    const float* Us = Um + sl * 2048;

    #pragma unroll
    for (int iter = 0; iter < 4; ++iter) {
        const int i = t + iter * 256;      // 0..1023 element pairs
        const int e0 = 2 * i;              // 0..2046
        const int dl = e0 >> 4, b0 = e0 & 15;
        const float2 v = *(const float2*)(Us + e0);
        const float f0 = v.x * inv_s[b0];
        const float f1 = v.y * inv_s[b0 + 1];
        *(uint*)(uh + e0) = (uint)f2h(f0) | ((uint)f2h(f1) << 16);
        tr[b0][dl]     = f2bf(f0);
        tr[b0 + 1][dl] = f2bf(f1);
    }
    __syncthreads();
    {
        const int b = t >> 4, doff = (t & 15) * 8;
        uint4 val;
        val.x = (uint)tr[b][doff + 0] | ((uint)tr[b][doff + 1] << 16);
        val.y = (uint)tr[b][doff + 2] | ((uint)tr[b][doff + 3] << 16);
        val.z = (uint)tr[b][doff + 4] | ((uint)tr[b][doff + 5] << 16);
        val.w = (uint)tr[b][doff + 6] | ((uint)tr[b][doff + 7] << 16);
        *(uint4*)(ut + (long)b * DD + doff) = val;
    }
    if (blk == 0 && t == 0) *loss_slot = 0.f;
}

// ---------------------------------------------------------------------------
// K2 w_gram: blocks [0,1024) = Gram tiles G[e][f] = Ue^T Uf (bf16 MFMA,
//            round-1-verified); blocks [1024,2048) = w-direct per token:
//            w[n][d] = sum_k sum_b u_fp16[e_k][d][b] * h[n][k][b] via dot2.
// ---------------------------------------------------------------------------
__global__ __launch_bounds__(256) void w_gram(
    const float* __restrict__ h_sparse,
    const int*   __restrict__ topk,
    void* __restrict__ ws,
    float* __restrict__ out)
{
    const int t = threadIdx.x;
    const int wave = t >> 6, lane = t & 63;
    const int quad = lane >> 4, l15 = lane & 15;

    if (blockIdx.x < 1024) {
        // ---- Gram: block handles (e, f-group); wave handles one f ----
        const int gblk = blockIdx.x;
        const int ge = gblk >> 4;
        const int gf = (gblk & 15) * 4 + wave;

        const ushort* utp = (const ushort*)((const char*)ws + UT_B);
        const ushort* ue = utp + (long)ge * BB * DD + (long)l15 * DD + quad * 8;
        const ushort* uf = utp + (long)gf * BB * DD + (long)l15 * DD + quad * 8;

        f32x4 acc = {0.f, 0.f, 0.f, 0.f};
        #pragma unroll
        for (int dblk = 0; dblk < 16; ++dblk) {
            const short8 ga = *(const short8*)(ue + dblk * 32);   // A[b=l15][d]
            const short8 gb = *(const short8*)(uf + dblk * 32);   // B[d][b'=l15]
            acc = __builtin_amdgcn_mfma_f32_16x16x32_bf16(ga, gb, acc, 0, 0, 0);
        }
        // C layout: col = lane&15, row = (lane>>4)*4 + r -> G[e][f][b][b']
        float* G = (float*)((char*)ws + GRAM_B) + (((long)ge * MM + gf) << 8);
        #pragma unroll
        for (int r = 0; r < 4; ++r)
            G[(quad * 4 + r) * 16 + l15] = acc[r];
    } else {
        // ---- w-direct: 8 tokens per block; thread t owns d = 2t, 2t+1 ----
        const int n0 = (blockIdx.x - 1024) * 8;

        __shared__ uint hs2[8 * 32];   // half2-packed h: [tok][k*8 + bpair]
        __shared__ int  eidx[8 * 4];

        if (t < 32) eidx[t] = topk[n0 * 4 + t];
        {
            const float2 hv = *(const float2*)(h_sparse + (long)n0 * 64 + t * 2);
            half2v p; p.x = (_Float16)hv.x; p.y = (_Float16)hv.y;
            hs2[t] = __builtin_bit_cast(uint, p);
        }
        __syncthreads();

        const ushort* uh = (const ushort*)((const char*)ws + U_B);

        #pragma unroll 2
        for (int tok = 0; tok < 8; ++tok) {
            const int n = n0 + tok;
            float a0 = 0.f, a1 = 0.f;
            #pragma unroll
            for (int k = 0; k < 4; ++k) {
                const int e = eidx[tok * 4 + k];
                // 64 B = rows d=2t (16 f16) and d=2t+1 (16 f16)
                const uint4* up = (const uint4*)(uh + (long)e * DD * BB + t * 32);
                const uint4 q0 = up[0], q1 = up[1];   // row 2t
                const uint4 q2 = up[2], q3 = up[3];   // row 2t+1
                const uint* hp = &hs2[tok * 32 + k * 8];
                a0 = dot2h(q0.x, hp[0], a0);
                a0 = dot2h(q0.y, hp[1], a0);
                a0 = dot2h(q0.z, hp[2], a0);
                a0 = dot2h(q0.w, hp[3], a0);
                a0 = dot2h(q1.x, hp[4], a0);
                a0 = dot2h(q1.y, hp[5], a0);
                a0 = dot2h(q1.z, hp[6], a0);
                a0 = dot2h(q1.w, hp[7], a0);
                a1 = dot2h(q2.x, hp[0], a1);
                a1 = dot2h(q2.y, hp[1], a1);
                a1 = dot2h(q2.z, hp[2], a1);
                a1 = dot2h(q2.w, hp[3], a1);
                a1 = dot2h(q3.x, hp[4], a1);
                a1 = dot2h(q3.y, hp[5], a1);
                a1 = dot2h(q3.z, hp[6], a1);
                a1 = dot2h(q3.w, hp[7], a1);
            }
            *(float2*)(out + (long)n * DD + t * 2) = make_float2(a0, a1);
        }
    }
}

// ---------------------------------------------------------------------------
// K3 loss_gram: recon[n,k,b] = sum_j sum_b' G[ek][ej][b][b'] h[n,j,b'].
// 256 blocks; wave handles 8 tokens serially, lane = (k=quad, b=l15).
// (round-1-verified code)
// ---------------------------------------------------------------------------
__global__ __launch_bounds__(256) void loss_gram(
    const float* __restrict__ h_sparse,
    const int*   __restrict__ topk,
    void* __restrict__ ws,
    float* __restrict__ out)
{
    const int t = threadIdx.x;
    const int wave = t >> 6, lane = t & 63;
    const int quad = lane >> 4, l15 = lane & 15;
    const float* G = (const float*)((const char*)ws + GRAM_B);

    __shared__ float loss_blk;
    if (t == 0) loss_blk = 0.f;
    __syncthreads();

    float lsum = 0.f;
    const int wgid = blockIdx.x * 4 + wave;              // 0..1023, 8 tokens each
    for (int i = 0; i < 8; ++i) {
        const int n = __builtin_amdgcn_readfirstlane(wgid * 8 + i);
        const int4 tk = *(const int4*)(topk + n * 4);
        const int ek = quad == 0 ? tk.x : quad == 1 ? tk.y : quad == 2 ? tk.z : tk.w;
        const float* hn = h_sparse + (long)n * (KK * BB);

        float recon = 0.f;
        #pragma unroll
        for (int j = 0; j < 4; ++j) {
            const int ej = j == 0 ? tk.x : j == 1 ? tk.y : j == 2 ? tk.z : tk.w;
            const float* Grow = G + (((long)(ek * MM + ej)) << 8) + l15 * 16;
            const float4 g0 = *(const float4*)(Grow + 0);
            const float4 g1 = *(const float4*)(Grow + 4);
            const float4 g2 = *(const float4*)(Grow + 8);
            const float4 g3 = *(const float4*)(Grow + 12);
            const float4 h0 = *(const float4*)(hn + j * 16 + 0);
            const float4 h1 = *(const float4*)(hn + j * 16 + 4);
            const float4 h2 = *(const float4*)(hn + j * 16 + 8);
            const float4 h3 = *(const float4*)(hn + j * 16 + 12);
            recon += g0.x * h0.x + g0.y * h0.y + g0.z * h0.z + g0.w * h0.w;
            recon += g1.x * h1.x + g1.y * h1.y + g1.z * h1.z + g1.w * h1.w;
            recon += g2.x * h2.x + g2.y * h2.y + g2.z * h2.z + g2.w * h2.w;
            recon += g3.x * h3.x + g3.y * h3.y + g3.z * h3.z + g3.w * h3.w;
        }
        const float hv = hn[quad * 16 + l15];
        const float d = recon - hv;
        lsum += d * d;
    }
    #pragma unroll
    for (int off = 32; off > 0; off >>= 1) lsum += __shfl_xor(lsum, off, 64);
    if (lane == 0 && lsum != 0.f) atomicAdd(&loss_blk, lsum);
    __syncthreads();
    if (t == 0 && loss_blk != 0.f)
        atomicAdd(out + (long)NN * DD, loss_blk * (1.0f / ((float)NN * KK * BB)));
}

// ---------------------------------------------------------------------------
// Fallback (round-1 proven): tiny workspace
// ---------------------------------------------------------------------------
__global__ __launch_bounds__(256) void norm_kernel(
    const float* __restrict__ U, float* __restrict__ inv_norm,
    float* __restrict__ loss_slot)
{
    const int m = blockIdx.x;
    const int t = threadIdx.x;
    const float* Um = U + (long)m * DP1 * BB;
    float acc = 0.f;
    for (int idx = t; idx < DP1 * BB; idx += 256) {
        float v = Um[idx];
        acc += v * v;
    }
    __shared__ float s[256];
    s[t] = acc;
    __syncthreads();
    if (t < BB) {
        float tot = 0.f;
        #pragma unroll
        for (int j = 0; j < 16; ++j) tot += s[t + 16 * j];
        inv_norm[m * BB + t] = rsqrtf(tot);
    }
    if (m == 0 && t == 0) *loss_slot = 0.f;
}

__global__ __launch_bounds__(256) void dense_write_kernel(
    const float* __restrict__ h_sparse,
    const int*   __restrict__ topk,
    const float* __restrict__ U,
    const float* __restrict__ inv_norm,
    float* __restrict__ out)
{
    const int n = blockIdx.x;
    const int t = threadIdx.x;

    __shared__ float hs[KK * BB];
    __shared__ float ho[KK * BB];
    __shared__ float inv_s[KK * BB];
    __shared__ int   eidx[KK];
    __shared__ float w_s[DD];
    __shared__ float red[256];

    if (t < KK) eidx[t] = topk[n * KK + t];
    __syncthreads();
    if (t < KK * BB) {
        const int k = t / BB, b = t % BB;
        const float h  = h_sparse[(long)n * KK * BB + t];
        const float iv = inv_norm[eidx[k] * BB + b];
        ho[t]    = h;
        inv_s[t] = iv;
        hs[t]    = h * iv;
    }
    __syncthreads();

    #pragma unroll
    for (int dd = 0; dd < 2; ++dd) {
        const int d = t + dd * 256;
        float w = 0.f;
        #pragma unroll
        for (int k = 0; k < KK; ++k) {
            const float4* row = (const float4*)(U + ((long)eidx[k] * DP1 + d) * BB);
            #pragma unroll
            for (int q = 0; q < 4; ++q) {
                const float4 u4 = row[q];
                w += u4.x * hs[k * BB + 4 * q + 0];
                w += u4.y * hs[k * BB + 4 * q + 1];
                w += u4.z * hs[k * BB + 4 * q + 2];
                w += u4.w * hs[k * BB + 4 * q + 3];
            }
        }
        w_s[d] = w;
        out[(long)n * DD + d] = w;
    }
    __syncthreads();

    {
        const int pair = t & 63;
        const int k = pair >> 4, b = pair & 15;
        const int ch = t >> 6;
        const float* Ucol = U + (long)eidx[k] * DP1 * BB + b;
        float p = 0.f;
        #pragma unroll 8
        for (int d = ch * 128; d < ch * 128 + 128; ++d) {
            p += Ucol[(long)d * BB] * w_s[d];
        }
        red[t] = p;
    }
    __syncthreads();

    if (t < 64) {
        const float recon = (red[t] + red[t + 64] + red[t + 128] + red[t + 192]) * inv_s[t];
        const float diff  = recon - ho[t];
        float sq = diff * diff;
        #pragma unroll
        for (int off = 32; off > 0; off >>= 1) sq += __shfl_down(sq, off, 64);
        if (t == 0) {
            atomicAdd(out + (long)NN * DD, sq * (1.0f / ((float)NN * KK * BB)));
        }
    }
}

// ---------------------------------------------------------------------------

extern "C" void kernel_launch(void* const* d_in, const int* in_sizes, int n_in,
                              void* d_out, int out_size, void* d_ws, size_t ws_size,
                              hipStream_t stream) {
    const float* h_sparse = (const float*)d_in[0];
    const int*   topk     = (const int*)d_in[1];
    const float* U        = (const float*)d_in[2];
    float* out = (float*)d_out;

    if (ws_size >= (size_t)WS_NEED) {
        hipLaunchKernelGGL(prep2, dim3(256), dim3(256), 0, stream,
                           U, d_ws, out + (long)NN * DD);
        hipLaunchKernelGGL(w_gram, dim3(2048), dim3(256), 0, stream,
                           h_sparse, topk, d_ws, out);
        hipLaunchKernelGGL(loss_gram, dim3(256), dim3(256), 0, stream,
                           h_sparse, topk, d_ws, out);
    } else {
        float* inv_norm = (float*)d_ws;
        hipLaunchKernelGGL(norm_kernel, dim3(MM), dim3(256), 0, stream,
                           U, inv_norm, out + (long)NN * DD);
        hipLaunchKernelGGL(dense_write_kernel, dim3(NN), dim3(256), 0, stream,
                           h_sparse, topk, U, inv_norm, out);
    }
}

// Round 6
// 141.655 us; speedup vs baseline: 1.0168x; 1.0168x over previous
//
#include <hip/hip_runtime.h>

#define DD 512
#define MM 64
#define BB 16
#define NN 8192
#define KK 4
#define DP1 513

// ws byte offsets (compact layout)
#define U_B    0                      // fp16 u[m][d][b], 1 MB
#define UT_B   1048576                // bf16 ut[m][b][d], 1 MB
#define GRAM_B 2097152                // fp32 G[e][f][16][16], 4 MB
#define WS_NEED 6291456

typedef unsigned int uint;
typedef unsigned short ushort;
typedef __attribute__((ext_vector_type(8))) short short8;
typedef __attribute__((ext_vector_type(4))) float f32x4;
typedef __attribute__((ext_vector_type(2))) _Float16 half2v;

__device__ __forceinline__ ushort f2bf(float f) {
    uint u = __builtin_bit_cast(uint, f);
    uint r = (u + 0x7FFFu + ((u >> 16) & 1u)) >> 16;
    return (ushort)r;
}
__device__ __forceinline__ ushort f2h(float f) {
    _Float16 h = (_Float16)f;
    return __builtin_bit_cast(ushort, h);
}

// dot2: c += a.x*b.x + a.y*b.y with fp16 inputs, fp32 accumulate
__device__ __forceinline__ float dot2h(uint a, uint b, float c) {
#if __has_builtin(__builtin_amdgcn_fdot2)
    return __builtin_amdgcn_fdot2(__builtin_bit_cast(half2v, a),
                                  __builtin_bit_cast(half2v, b), c, false);
#else
    half2v av = __builtin_bit_cast(half2v, a);
    half2v bv = __builtin_bit_cast(half2v, b);
    return c + (float)av.x * (float)bv.x + (float)av.y * (float)bv.y;
#endif
}

// ---------------------------------------------------------------------------
// K1 prep2: 256 blocks (4 per expert, d-slice of 128).
// Writes u (fp16, [e][d][b]) and ut (bf16, [e][b][d]); zeroes loss slot.
// NOTE: norm loop must stay SCALAR with stride 256 — per-column (b = i&15)
// partial sums rely on stride ≡ 0 (mod 16). float4 here mixes columns (r5 bug).
// ---------------------------------------------------------------------------
__global__ __launch_bounds__(256) void prep2(
    const float* __restrict__ U,
    void* __restrict__ ws,
    float* __restrict__ loss_slot)
{
    const int blk = blockIdx.x, t = threadIdx.x;
    const int m = blk >> 2, sl = blk & 3;
    const float* Um = U + (long)m * DP1 * BB;

    __shared__ float red[256];
    __shared__ float inv_s[BB];
    __shared__ ushort tr[BB][136];

    float a = 0.f;
    for (int i = t; i < DP1 * BB; i += 256) { float v = Um[i]; a += v * v; }
    red[t] = a;
    __syncthreads();
    if (t < BB) {
        float tot = 0.f;
        #pragma unroll
        for (int j = 0; j < 16; ++j) tot += red[t + 16 * j];
        inv_s[t] = rsqrtf(tot);
    }
    __syncthreads();

    ushort* uh = (ushort*)((char*)ws + U_B) + (long)m * DD * BB + sl * 2048;
    ushort* ut = (ushort*)((char*)ws + UT_B) + (long)m * BB * DD + sl * 128;
    const float* Us = Um + sl * 2048;

    #pragma unroll
    for (int iter = 0; iter < 4; ++iter) {
        const int i = t + iter * 256;      // 0..1023 element pairs
        const int e0 = 2 * i;              // 0..2046
        const int dl = e0 >> 4, b0 = e0 & 15;
        const float2 v = *(const float2*)(Us + e0);
        const float f0 = v.x * inv_s[b0];
        const float f1 = v.y * inv_s[b0 + 1];
        *(uint*)(uh + e0) = (uint)f2h(f0) | ((uint)f2h(f1) << 16);
        tr[b0][dl]     = f2bf(f0);
        tr[b0 + 1][dl] = f2bf(f1);
    }
    __syncthreads();
    {
        const int b = t >> 4, doff = (t & 15) * 8;
        uint4 val;
        val.x = (uint)tr[b][doff + 0] | ((uint)tr[b][doff + 1] << 16);
        val.y = (uint)tr[b][doff + 2] | ((uint)tr[b][doff + 3] << 16);
        val.z = (uint)tr[b][doff + 4] | ((uint)tr[b][doff + 5] << 16);
        val.w = (uint)tr[b][doff + 6] | ((uint)tr[b][doff + 7] << 16);
        *(uint4*)(ut + (long)b * DD + doff) = val;
    }
    if (blk == 0 && t == 0) *loss_slot = 0.f;
}

// ---------------------------------------------------------------------------
// K2 w_gram: blocks [0,1024) = Gram tiles G[e][f] = Ue^T Uf (bf16 MFMA);
//            blocks [1024,3072) = w-direct, 4 tokens per block:
//            w[n][d] = sum_k sum_b u_fp16[e_k][d][b] * h[n][k][b] via dot2.
//            All 16 u-row loads per token issued before the dot chains
//            (8 independent chains) to maximize memory-level parallelism.
// ---------------------------------------------------------------------------
__global__ __launch_bounds__(256) void w_gram(
    const float* __restrict__ h_sparse,
    const int*   __restrict__ topk,
    void* __restrict__ ws,
    float* __restrict__ out)
{
    const int t = threadIdx.x;
    const int wave = t >> 6, lane = t & 63;
    const int quad = lane >> 4, l15 = lane & 15;

    if (blockIdx.x < 1024) {
        // ---- Gram: block handles (e, f-group); wave handles one f ----
        const int gblk = blockIdx.x;
        const int ge = gblk >> 4;
        const int gf = (gblk & 15) * 4 + wave;

        const ushort* utp = (const ushort*)((const char*)ws + UT_B);
        const ushort* ue = utp + (long)ge * BB * DD + (long)l15 * DD + quad * 8;
        const ushort* uf = utp + (long)gf * BB * DD + (long)l15 * DD + quad * 8;

        f32x4 acc = {0.f, 0.f, 0.f, 0.f};
        #pragma unroll
        for (int dblk = 0; dblk < 16; ++dblk) {
            const short8 ga = *(const short8*)(ue + dblk * 32);   // A[b=l15][d]
            const short8 gb = *(const short8*)(uf + dblk * 32);   // B[d][b'=l15]
            acc = __builtin_amdgcn_mfma_f32_16x16x32_bf16(ga, gb, acc, 0, 0, 0);
        }
        // C layout: col = lane&15, row = (lane>>4)*4 + r -> G[e][f][b][b']
        float* G = (float*)((char*)ws + GRAM_B) + (((long)ge * MM + gf) << 8);
        #pragma unroll
        for (int r = 0; r < 4; ++r)
            G[(quad * 4 + r) * 16 + l15] = acc[r];
    } else {
        // ---- w-direct: 4 tokens per block; thread t owns d = 2t, 2t+1 ----
        const int n0 = (blockIdx.x - 1024) * 4;

        __shared__ uint hs2[4 * 32];   // half2-packed h: [tok][k*8 + bpair]
        __shared__ int  eidx[4 * 4];

        if (t < 16) eidx[t] = topk[n0 * 4 + t];
        if (t < 128) {
            const float2 hv = *(const float2*)(h_sparse + (long)n0 * 64 + t * 2);
            half2v p; p.x = (_Float16)hv.x; p.y = (_Float16)hv.y;
            hs2[t] = __builtin_bit_cast(uint, p);
        }
        __syncthreads();

        const ushort* uh = (const ushort*)((const char*)ws + U_B);

        #pragma unroll
        for (int tok = 0; tok < 4; ++tok) {
            const int n = n0 + tok;
            const int e0 = eidx[tok * 4 + 0], e1 = eidx[tok * 4 + 1];
            const int e2 = eidx[tok * 4 + 2], e3 = eidx[tok * 4 + 3];
            const uint4* p0 = (const uint4*)(uh + (long)e0 * DD * BB + t * 32);
            const uint4* p1 = (const uint4*)(uh + (long)e1 * DD * BB + t * 32);
            const uint4* p2 = (const uint4*)(uh + (long)e2 * DD * BB + t * 32);
            const uint4* p3 = (const uint4*)(uh + (long)e3 * DD * BB + t * 32);
            // issue all 16 loads before any use (forces them in flight together)
            const uint4 A0 = p0[0], A1 = p0[1], A2 = p0[2], A3 = p0[3];
            const uint4 B0 = p1[0], B1 = p1[1], B2 = p1[2], B3 = p1[3];
            const uint4 C0 = p2[0], C1 = p2[1], C2 = p2[2], C3 = p2[3];
            const uint4 D0 = p3[0], D1 = p3[1], D2 = p3[2], D3 = p3[3];
            const uint* hp = &hs2[tok * 32];

            // 8 independent dot2 chains of length 8
            float x0, x1, x2, x3, y0, y1, y2, y3;
            x0 = dot2h(A0.x, hp[0], 0.f);  x0 = dot2h(A0.y, hp[1], x0);
            x0 = dot2h(A0.z, hp[2], x0);   x0 = dot2h(A0.w, hp[3], x0);
            x0 = dot2h(A1.x, hp[4], x0);   x0 = dot2h(A1.y, hp[5], x0);
            x0 = dot2h(A1.z, hp[6], x0);   x0 = dot2h(A1.w, hp[7], x0);
            y0 = dot2h(A2.x, hp[0], 0.f);  y0 = dot2h(A2.y, hp[1], y0);
            y0 = dot2h(A2.z, hp[2], y0);   y0 = dot2h(A2.w, hp[3], y0);
            y0 = dot2h(A3.x, hp[4], y0);   y0 = dot2h(A3.y, hp[5], y0);
            y0 = dot2h(A3.z, hp[6], y0);   y0 = dot2h(A3.w, hp[7], y0);

            x1 = dot2h(B0.x, hp[8], 0.f);  x1 = dot2h(B0.y, hp[9], x1);
            x1 = dot2h(B0.z, hp[10], x1);  x1 = dot2h(B0.w, hp[11], x1);
            x1 = dot2h(B1.x, hp[12], x1);  x1 = dot2h(B1.y, hp[13], x1);
            x1 = dot2h(B1.z, hp[14], x1);  x1 = dot2h(B1.w, hp[15], x1);
            y1 = dot2h(B2.x, hp[8], 0.f);  y1 = dot2h(B2.y, hp[9], y1);
            y1 = dot2h(B2.z, hp[10], y1);  y1 = dot2h(B2.w, hp[11], y1);
            y1 = dot2h(B3.x, hp[12], y1);  y1 = dot2h(B3.y, hp[13], y1);
            y1 = dot2h(B3.z, hp[14], y1);  y1 = dot2h(B3.w, hp[15], y1);

            x2 = dot2h(C0.x, hp[16], 0.f); x2 = dot2h(C0.y, hp[17], x2);
            x2 = dot2h(C0.z, hp[18], x2);  x2 = dot2h(C0.w, hp[19], x2);
            x2 = dot2h(C1.x, hp[20], x2);  x2 = dot2h(C1.y, hp[21], x2);
            x2 = dot2h(C1.z, hp[22], x2);  x2 = dot2h(C1.w, hp[23], x2);
            y2 = dot2h(C2.x, hp[16], 0.f); y2 = dot2h(C2.y, hp[17], y2);
            y2 = dot2h(C2.z, hp[18], y2);  y2 = dot2h(C2.w, hp[19], y2);
            y2 = dot2h(C3.x, hp[20], y2);  y2 = dot2h(C3.y, hp[21], y2);
            y2 = dot2h(C3.z, hp[22], y2);  y2 = dot2h(C3.w, hp[23], y2);

            x3 = dot2h(D0.x, hp[24], 0.f); x3 = dot2h(D0.y, hp[25], x3);
            x3 = dot2h(D0.z, hp[26], x3);  x3 = dot2h(D0.w, hp[27], x3);
            x3 = dot2h(D1.x, hp[28], x3);  x3 = dot2h(D1.y, hp[29], x3);
            x3 = dot2h(D1.z, hp[30], x3);  x3 = dot2h(D1.w, hp[31], x3);
            y3 = dot2h(D2.x, hp[24], 0.f); y3 = dot2h(D2.y, hp[25], y3);
            y3 = dot2h(D2.z, hp[26], y3);  y3 = dot2h(D2.w, hp[27], y3);
            y3 = dot2h(D3.x, hp[28], y3);  y3 = dot2h(D3.y, hp[29], y3);
            y3 = dot2h(D3.z, hp[30], y3);  y3 = dot2h(D3.w, hp[31], y3);

            const float a0 = (x0 + x1) + (x2 + x3);
            const float a1 = (y0 + y1) + (y2 + y3);
            *(float2*)(out + (long)n * DD + t * 2) = make_float2(a0, a1);
        }
    }
}

// ---------------------------------------------------------------------------
// K3 loss_gram: recon[n,k,b] = sum_j sum_b' G[ek][ej][b][b'] h[n,j,b'].
// 1024 blocks; wave handles 2 tokens, lane = (k=quad, b=l15).
// ---------------------------------------------------------------------------
__global__ __launch_bounds__(256) void loss_gram(
    const float* __restrict__ h_sparse,
    const int*   __restrict__ topk,
    void* __restrict__ ws,
    float* __restrict__ out)
{
    const int t = threadIdx.x;
    const int wave = t >> 6, lane = t & 63;
    const int quad = lane >> 4, l15 = lane & 15;
    const float* G = (const float*)((const char*)ws + GRAM_B);

    __shared__ float loss_blk;
    if (t == 0) loss_blk = 0.f;
    __syncthreads();

    float lsum = 0.f;
    const int wgid = blockIdx.x * 4 + wave;              // 0..4095, 2 tokens each
    for (int i = 0; i < 2; ++i) {
        const int n = __builtin_amdgcn_readfirstlane(wgid * 2 + i);
        const int4 tk = *(const int4*)(topk + n * 4);
        const int ek = quad == 0 ? tk.x : quad == 1 ? tk.y : quad == 2 ? tk.z : tk.w;
        const float* hn = h_sparse + (long)n * (KK * BB);

        float recon = 0.f;
        #pragma unroll
        for (int j = 0; j < 4; ++j) {
            const int ej = j == 0 ? tk.x : j == 1 ? tk.y : j == 2 ? tk.z : tk.w;
            const float* Grow = G + (((long)(ek * MM + ej)) << 8) + l15 * 16;
            const float4 g0 = *(const float4*)(Grow + 0);
            const float4 g1 = *(const float4*)(Grow + 4);
            const float4 g2 = *(const float4*)(Grow + 8);
            const float4 g3 = *(const float4*)(Grow + 12);
            const float4 h0 = *(const float4*)(hn + j * 16 + 0);
            const float4 h1 = *(const float4*)(hn + j * 16 + 4);
            const float4 h2 = *(const float4*)(hn + j * 16 + 8);
            const float4 h3 = *(const float4*)(hn + j * 16 + 12);
            recon += g0.x * h0.x + g0.y * h0.y + g0.z * h0.z + g0.w * h0.w;
            recon += g1.x * h1.x + g1.y * h1.y + g1.z * h1.z + g1.w * h1.w;
            recon += g2.x * h2.x + g2.y * h2.y + g2.z * h2.z + g2.w * h2.w;
            recon += g3.x * h3.x + g3.y * h3.y + g3.z * h3.z + g3.w * h3.w;
        }
        const float hv = hn[quad * 16 + l15];
        const float d = recon - hv;
        lsum += d * d;
    }
    #pragma unroll
    for (int off = 32; off > 0; off >>= 1) lsum += __shfl_xor(lsum, off, 64);
    if (lane == 0 && lsum != 0.f) atomicAdd(&loss_blk, lsum);
    __syncthreads();
    if (t == 0 && loss_blk != 0.f)
        atomicAdd(out + (long)NN * DD, loss_blk * (1.0f / ((float)NN * KK * BB)));
}

// ---------------------------------------------------------------------------
// Fallback (round-1 proven): tiny workspace
// ---------------------------------------------------------------------------
__global__ __launch_bounds__(256) void norm_kernel(
    const float* __restrict__ U, float* __restrict__ inv_norm,
    float* __restrict__ loss_slot)
{
    const int m = blockIdx.x;
    const int t = threadIdx.x;
    const float* Um = U + (long)m * DP1 * BB;
    float acc = 0.f;
    for (int idx = t; idx < DP1 * BB; idx += 256) {
        float v = Um[idx];
        acc += v * v;
    }
    __shared__ float s[256];
    s[t] = acc;
    __syncthreads();
    if (t < BB) {
        float tot = 0.f;
        #pragma unroll
        for (int j = 0; j < 16; ++j) tot += s[t + 16 * j];
        inv_norm[m * BB + t] = rsqrtf(tot);
    }
    if (m == 0 && t == 0) *loss_slot = 0.f;
}

__global__ __launch_bounds__(256) void dense_write_kernel(
    const float* __restrict__ h_sparse,
    const int*   __restrict__ topk,
    const float* __restrict__ U,
    const float* __restrict__ inv_norm,
    float* __restrict__ out)
{
    const int n = blockIdx.x;
    const int t = threadIdx.x;

    __shared__ float hs[KK * BB];
    __shared__ float ho[KK * BB];
    __shared__ float inv_s[KK * BB];
    __shared__ int   eidx[KK];
    __shared__ float w_s[DD];
    __shared__ float red[256];

    if (t < KK) eidx[t] = topk[n * KK + t];
    __syncthreads();
    if (t < KK * BB) {
        const int k = t / BB, b = t % BB;
        const float h  = h_sparse[(long)n * KK * BB + t];
        const float iv = inv_norm[eidx[k] * BB + b];
        ho[t]    = h;
        inv_s[t] = iv;
        hs[t]    = h * iv;
    }
    __syncthreads();

    #pragma unroll
    for (int dd = 0; dd < 2; ++dd) {
        const int d = t + dd * 256;
        float w = 0.f;
        #pragma unroll
        for (int k = 0; k < KK; ++k) {
            const float4* row = (const float4*)(U + ((long)eidx[k] * DP1 + d) * BB);
            #pragma unroll
            for (int q = 0; q < 4; ++q) {
                const float4 u4 = row[q];
                w += u4.x * hs[k * BB + 4 * q + 0];
                w += u4.y * hs[k * BB + 4 * q + 1];
                w += u4.z * hs[k * BB + 4 * q + 2];
                w += u4.w * hs[k * BB + 4 * q + 3];
            }
        }
        w_s[d] = w;
        out[(long)n * DD + d] = w;
    }
    __syncthreads();

    {
        const int pair = t & 63;
        const int k = pair >> 4, b = pair & 15;
        const int ch = t >> 6;
        const float* Ucol = U + (long)eidx[k] * DP1 * BB + b;
        float p = 0.f;
        #pragma unroll 8
        for (int d = ch * 128; d < ch * 128 + 128; ++d) {
            p += Ucol[(long)d * BB] * w_s[d];
        }
        red[t] = p;
    }
    __syncthreads();

    if (t < 64) {
        const float recon = (red[t] + red[t + 64] + red[t + 128] + red[t + 192]) * inv_s[t];
        const float diff  = recon - ho[t];
        float sq = diff * diff;
        #pragma unroll
        for (int off = 32; off > 0; off >>= 1) sq += __shfl_down(sq, off, 64);
        if (t == 0) {
            atomicAdd(out + (long)NN * DD, sq * (1.0f / ((float)NN * KK * BB)));
        }
    }
}

// ---------------------------------------------------------------------------

extern "C" void kernel_launch(void* const* d_in, const int* in_sizes, int n_in,
                              void* d_out, int out_size, void* d_ws, size_t ws_size,
                              hipStream_t stream) {
    const float* h_sparse = (const float*)d_in[0];
    const int*   topk     = (const int*)d_in[1];
    const float* U        = (const float*)d_in[2];
    float* out = (float*)d_out;

    if (ws_size >= (size_t)WS_NEED) {
        hipLaunchKernelGGL(prep2, dim3(256), dim3(256), 0, stream,
                           U, d_ws, out + (long)NN * DD);
        hipLaunchKernelGGL(w_gram, dim3(3072), dim3(256), 0, stream,
                           h_sparse, topk, d_ws, out);
        hipLaunchKernelGGL(loss_gram, dim3(1024), dim3(256), 0, stream,
                           h_sparse, topk, d_ws, out);
    } else {
        float* inv_norm = (float*)d_ws;
        hipLaunchKernelGGL(norm_kernel, dim3(MM), dim3(256), 0, stream,
                           U, inv_norm, out + (long)NN * DD);
        hipLaunchKernelGGL(dense_write_kernel, dim3(NN), dim3(256), 0, stream,
                           h_sparse, topk, U, inv_norm, out);
    }
}

// Round 7
// 128.726 us; speedup vs baseline: 1.1190x; 1.1004x over previous
//
#include <hip/hip_runtime.h>

#define DD 512
#define MM 64
#define BB 16
#define NN 8192
#define KK 4
#define DP1 513
#define CAP 1024
#define NPAIR (NN * KK)

// ws byte offsets
#define CNT_B  0                      // 64 int expert counts (256 B)
#define BKT_B  33024                  // 64*1024 ushort pair ids (128 KB)
#define U_B    164096                 // bf16 u[m][d][b], 1 MB
#define UT_B   1212672                // bf16 ut[m][b][d], 1 MB
#define GRAM_B 2261248                // fp32 G[e][f][16][16], 4 MB (old wbf slot)
#define PART_B 10649856               // bf16 part[k][n][d], 32 MB
#define WS_NEED 44204288

typedef unsigned int uint;
typedef unsigned short ushort;
typedef __attribute__((ext_vector_type(8))) short short8;
typedef __attribute__((ext_vector_type(4))) float f32x4;

__device__ __forceinline__ ushort f2bf(float f) {
    uint u = __builtin_bit_cast(uint, f);
    uint r = (u + 0x7FFFu + ((u >> 16) & 1u)) >> 16;
    return (ushort)r;
}
__device__ __forceinline__ float bf2f(ushort s) {
    return __builtin_bit_cast(float, (uint)s << 16);
}

// ---------------------------------------------------------------------------
// K1 prep_build: blocks 0-255 = prep (4 blocks/expert, d-slice of 128);
//                blocks 256-383 = counting sort (independent, concurrent).
// cnt[] must be zeroed before this kernel (memset).
// ---------------------------------------------------------------------------
__global__ __launch_bounds__(256) void prep_build(
    const float* __restrict__ U,
    const int*   __restrict__ topk,
    void* __restrict__ ws,
    float* __restrict__ loss_slot)
{
    const int blk = blockIdx.x, t = threadIdx.x;

    if (blk < 256) {
        // ---- prep: expert m, d-slice sl ----
        const int m = blk >> 2, sl = blk & 3;
        const float* Um = U + (long)m * DP1 * BB;

        __shared__ float red[256];
        __shared__ float inv_s[BB];
        __shared__ ushort tr[BB][136];

        float a = 0.f;
        for (int i = t; i < DP1 * BB; i += 256) { float v = Um[i]; a += v * v; }
        red[t] = a;
        __syncthreads();
        if (t < BB) {
            float tot = 0.f;
            #pragma unroll
            for (int j = 0; j < 16; ++j) tot += red[t + 16 * j];
            inv_s[t] = rsqrtf(tot);
        }
        __syncthreads();

        ushort* ub = (ushort*)((char*)ws + U_B) + (long)m * DD * BB + sl * 2048;
        ushort* ut = (ushort*)((char*)ws + UT_B) + (long)m * BB * DD + sl * 128;
        const float* Us = Um + sl * 2048;

        #pragma unroll
        for (int iter = 0; iter < 4; ++iter) {
            const int i = t + iter * 256;      // 0..1023 element pairs
            const int e0 = 2 * i;              // 0..2046
            const int dl = e0 >> 4, b0 = e0 & 15;
            const float2 v = *(const float2*)(Us + e0);
            const ushort bv0 = f2bf(v.x * inv_s[b0]);
            const ushort bv1 = f2bf(v.y * inv_s[b0 + 1]);
            *(uint*)(ub + e0) = (uint)bv0 | ((uint)bv1 << 16);
            tr[b0][dl]     = bv0;
            tr[b0 + 1][dl] = bv1;
        }
        __syncthreads();
        {
            const int b = t >> 4, doff = (t & 15) * 8;
            uint4 val;
            val.x = (uint)tr[b][doff + 0] | ((uint)tr[b][doff + 1] << 16);
            val.y = (uint)tr[b][doff + 2] | ((uint)tr[b][doff + 3] << 16);
            val.z = (uint)tr[b][doff + 4] | ((uint)tr[b][doff + 5] << 16);
            val.w = (uint)tr[b][doff + 6] | ((uint)tr[b][doff + 7] << 16);
            *(uint4*)(ut + (long)b * DD + doff) = val;
        }
    } else {
        // ---- build: counting sort chunk (blk-256) ----
        const int cblk = blk - 256;
        int* cnt = (int*)ws;
        ushort* bkt = (ushort*)((char*)ws + BKT_B);
        __shared__ int lc[MM], lb[MM];
        if (t < MM) lc[t] = 0;
        __syncthreads();
        const int p = cblk * 256 + t;
        const int e = topk[p];
        const int my = atomicAdd(&lc[e], 1);
        __syncthreads();
        if (t < MM) lb[t] = atomicAdd(&cnt[t], lc[t]);
        __syncthreads();
        bkt[e * CAP + lb[e] + my] = (ushort)p;
        if (cblk == 0 && t == 0) *loss_slot = 0.f;
    }
}

// ---------------------------------------------------------------------------
// K2 (MFMA): blocks [0,1024): part[k][n][d] = Un_e * h^T, wave-pair split
//            (round-3-proven, 127.3 us chain).
//            blocks [1024,2048): Gram tiles G[e][f] = Ue^T Uf (round-1-proven;
//            depends only on K1's ut, overlaps with the writes blocks).
// ---------------------------------------------------------------------------
__global__ __launch_bounds__(256) void pass_writes_mfma(
    const float* __restrict__ h_sparse, void* __restrict__ ws)
{
    const int wave = threadIdx.x >> 6, lane = threadIdx.x & 63;
    const int quad = lane >> 4, l15 = lane & 15;

    if (blockIdx.x < MM * 16) {
        const int e = blockIdx.x & 63, g = blockIdx.x >> 6;      // g in [0,16)
        const int wp = wave >> 1, half = wave & 1;

        const int* cnt = (const int*)ws;
        const ushort* bkt = (const ushort*)((const char*)ws + BKT_B);
        const ushort* Ue = (const ushort*)((const char*)ws + U_B) + (long)e * DD * BB;
        ushort* part = (ushort*)((char*)ws + PART_B);

        const int c  = cnt[e];
        const int lo = (c * g) >> 4;
        const int hi = (c * (g + 1)) >> 4;

        for (int base = lo + wp * 16; base < hi; base += 32) {
            const int pidx = base + l15;
            const bool valid = pidx < hi;
            const int id = valid ? (int)bkt[e * CAP + pidx] : 0;
            const int n = id >> 2, k = id & 3;

            short8 bfrag = (short8)0;
            if (quad < 2 && valid) {
                const float4* hp = (const float4*)(h_sparse + (long)id * BB + quad * 8);
                const float4 h0 = hp[0], h1 = hp[1];
                bfrag[0] = (short)f2bf(h0.x); bfrag[1] = (short)f2bf(h0.y);
                bfrag[2] = (short)f2bf(h0.z); bfrag[3] = (short)f2bf(h0.w);
                bfrag[4] = (short)f2bf(h1.x); bfrag[5] = (short)f2bf(h1.y);
                bfrag[6] = (short)f2bf(h1.z); bfrag[7] = (short)f2bf(h1.w);
            }
            ushort* prow = part + ((long)(k * NN + n) << 9);

            const int dt0 = half * 16;
            #pragma unroll 2
            for (int dt = dt0; dt < dt0 + 16; dt += 2) {
                short8 a0 = (short8)0, a1 = (short8)0;
                if (quad < 2) {
                    a0 = *(const short8*)(Ue + ((long)(dt * 16 + l15) << 4) + quad * 8);
                    a1 = *(const short8*)(Ue + ((long)((dt + 1) * 16 + l15) << 4) + quad * 8);
                }
                f32x4 z = {0.f, 0.f, 0.f, 0.f};
                f32x4 c0 = __builtin_amdgcn_mfma_f32_16x16x32_bf16(a0, bfrag, z, 0, 0, 0);
                f32x4 c1 = __builtin_amdgcn_mfma_f32_16x16x32_bf16(a1, bfrag, z, 0, 0, 0);

                uint p0x = (uint)f2bf(c0[0]) | ((uint)f2bf(c0[1]) << 16);
                uint p0y = (uint)f2bf(c0[2]) | ((uint)f2bf(c0[3]) << 16);
                uint p1x = (uint)f2bf(c1[0]) | ((uint)f2bf(c1[1]) << 16);
                uint p1y = (uint)f2bf(c1[2]) | ((uint)f2bf(c1[3]) << 16);
                uint q0x = __shfl_xor((int)p0x, 16, 64);
                uint q0y = __shfl_xor((int)p0y, 16, 64);
                uint q1x = __shfl_xor((int)p1x, 16, 64);
                uint q1y = __shfl_xor((int)p1y, 16, 64);

                if (valid) {
                    uint4 st;
                    int sdt;
                    if ((quad & 1) == 0) { st.x = p0x; st.y = p0y; st.z = q0x; st.w = q0y; sdt = dt; }
                    else                 { st.x = q1x; st.y = q1y; st.z = p1x; st.w = p1y; sdt = dt + 1; }
                    const int srow = (quad & 2) ? 8 : 0;
                    *(uint4*)(prow + sdt * 16 + srow) = st;
                }
            }
        }
    } else {
        // ---- Gram: block handles (e, f-group); wave handles one f ----
        const int gblk = blockIdx.x - MM * 16;         // 0..1023
        const int ge = gblk >> 4;
        const int gf = (gblk & 15) * 4 + wave;

        const ushort* utp = (const ushort*)((const char*)ws + UT_B);
        const ushort* ue = utp + (long)ge * BB * DD + (long)l15 * DD + quad * 8;
        const ushort* uf = utp + (long)gf * BB * DD + (long)l15 * DD + quad * 8;

        f32x4 acc = {0.f, 0.f, 0.f, 0.f};
        #pragma unroll
        for (int dblk = 0; dblk < 16; ++dblk) {
            const short8 ga = *(const short8*)(ue + dblk * 32);   // A[b=l15][d]
            const short8 gb = *(const short8*)(uf + dblk * 32);   // B[d][b'=l15]
            acc = __builtin_amdgcn_mfma_f32_16x16x32_bf16(ga, gb, acc, 0, 0, 0);
        }
        // C layout: col = lane&15, row = (lane>>4)*4 + r -> G[e][f][b][b']
        float* G = (float*)((char*)ws + GRAM_B) + (((long)ge * MM + gf) << 8);
        #pragma unroll
        for (int r = 0; r < 4; ++r)
            G[(quad * 4 + r) * 16 + l15] = acc[r];
    }
}

// ---------------------------------------------------------------------------
// K3: blocks [0,2048): w[n][d] = sum_k part[k][n][d] -> fp32 out (no wbf).
//     blocks [2048,3072): loss from Gram (round-6-proven, 1024-block form):
//     recon[n,k,b] = sum_j G[ek][ej][b,:]·h[n,j,:]; wave = 2 tokens.
// ---------------------------------------------------------------------------
__global__ __launch_bounds__(256) void reduce_loss(
    const float* __restrict__ h_sparse,
    const int*   __restrict__ topk,
    void* __restrict__ ws, float* __restrict__ out)
{
    const int t = threadIdx.x;

    if (blockIdx.x < NN * DD / 8 / 256) {
        const uint4* part4 = (const uint4*)((const char*)ws + PART_B);
        const int gsz = NN * DD / 8;
        const int gid = blockIdx.x * 256 + t;

        const uint4 v0 = part4[gid];
        const uint4 v1 = part4[(long)gsz + gid];
        const uint4 v2 = part4[2L * gsz + gid];
        const uint4 v3 = part4[3L * gsz + gid];

        float s[8];
        s[0] = bf2f((ushort)v0.x) + bf2f((ushort)v1.x) + bf2f((ushort)v2.x) + bf2f((ushort)v3.x);
        s[1] = bf2f((ushort)(v0.x >> 16)) + bf2f((ushort)(v1.x >> 16)) + bf2f((ushort)(v2.x >> 16)) + bf2f((ushort)(v3.x >> 16));
        s[2] = bf2f((ushort)v0.y) + bf2f((ushort)v1.y) + bf2f((ushort)v2.y) + bf2f((ushort)v3.y);
        s[3] = bf2f((ushort)(v0.y >> 16)) + bf2f((ushort)(v1.y >> 16)) + bf2f((ushort)(v2.y >> 16)) + bf2f((ushort)(v3.y >> 16));
        s[4] = bf2f((ushort)v0.z) + bf2f((ushort)v1.z) + bf2f((ushort)v2.z) + bf2f((ushort)v3.z);
        s[5] = bf2f((ushort)(v0.z >> 16)) + bf2f((ushort)(v1.z >> 16)) + bf2f((ushort)(v2.z >> 16)) + bf2f((ushort)(v3.z >> 16));
        s[6] = bf2f((ushort)v0.w) + bf2f((ushort)v1.w) + bf2f((ushort)v2.w) + bf2f((ushort)v3.w);
        s[7] = bf2f((ushort)(v0.w >> 16)) + bf2f((ushort)(v1.w >> 16)) + bf2f((ushort)(v2.w >> 16)) + bf2f((ushort)(v3.w >> 16));

        float4* out4 = (float4*)out;
        out4[(long)gid * 2 + 0] = make_float4(s[0], s[1], s[2], s[3]);
        out4[(long)gid * 2 + 1] = make_float4(s[4], s[5], s[6], s[7]);
    } else {
        // ---- loss from Gram: wave = 2 tokens, lane = (k=quad, b=l15) ----
        const int lblk = blockIdx.x - NN * DD / 8 / 256;   // 0..1023
        const int wave = t >> 6, lane = t & 63;
        const int quad = lane >> 4, l15 = lane & 15;
        const float* G = (const float*)((const char*)ws + GRAM_B);

        __shared__ float loss_blk;
        if (t == 0) loss_blk = 0.f;
        __syncthreads();

        float lsum = 0.f;
        const int wgid = lblk * 4 + wave;                  // 0..4095
        for (int i = 0; i < 2; ++i) {
            const int n = __builtin_amdgcn_readfirstlane(wgid * 2 + i);
            const int4 tk = *(const int4*)(topk + n * 4);
            const int ek = quad == 0 ? tk.x : quad == 1 ? tk.y : quad == 2 ? tk.z : tk.w;
            const float* hn = h_sparse + (long)n * (KK * BB);

            float recon = 0.f;
            #pragma unroll
            for (int j = 0; j < 4; ++j) {
                const int ej = j == 0 ? tk.x : j == 1 ? tk.y : j == 2 ? tk.z : tk.w;
                const float* Grow = G + (((long)(ek * MM + ej)) << 8) + l15 * 16;
                const float4 g0 = *(const float4*)(Grow + 0);
                const float4 g1 = *(const float4*)(Grow + 4);
                const float4 g2 = *(const float4*)(Grow + 8);
                const float4 g3 = *(const float4*)(Grow + 12);
                const float4 h0 = *(const float4*)(hn + j * 16 + 0);
                const float4 h1 = *(const float4*)(hn + j * 16 + 4);
                const float4 h2 = *(const float4*)(hn + j * 16 + 8);
                const float4 h3 = *(const float4*)(hn + j * 16 + 12);
                recon += g0.x * h0.x + g0.y * h0.y + g0.z * h0.z + g0.w * h0.w;
                recon += g1.x * h1.x + g1.y * h1.y + g1.z * h1.z + g1.w * h1.w;
                recon += g2.x * h2.x + g2.y * h2.y + g2.z * h2.z + g2.w * h2.w;
                recon += g3.x * h3.x + g3.y * h3.y + g3.z * h3.z + g3.w * h3.w;
            }
            const float hv = hn[quad * 16 + l15];
            const float d = recon - hv;
            lsum += d * d;
        }
        #pragma unroll
        for (int off = 32; off > 0; off >>= 1) lsum += __shfl_xor(lsum, off, 64);
        if (lane == 0 && lsum != 0.f) atomicAdd(&loss_blk, lsum);
        __syncthreads();
        if (t == 0 && loss_blk != 0.f)
            atomicAdd(out + (long)NN * DD, loss_blk * (1.0f / ((float)NN * KK * BB)));
    }
}

// ---------------------------------------------------------------------------
// Fallback (round-1 proven): tiny workspace
// ---------------------------------------------------------------------------
__global__ __launch_bounds__(256) void norm_kernel(
    const float* __restrict__ U, float* __restrict__ inv_norm,
    float* __restrict__ loss_slot)
{
    const int m = blockIdx.x;
    const int t = threadIdx.x;
    const float* Um = U + (long)m * DP1 * BB;
    float acc = 0.f;
    for (int idx = t; idx < DP1 * BB; idx += 256) {
        float v = Um[idx];
        acc += v * v;
    }
    __shared__ float s[256];
    s[t] = acc;
    __syncthreads();
    if (t < BB) {
        float tot = 0.f;
        #pragma unroll
        for (int j = 0; j < 16; ++j) tot += s[t + 16 * j];
        inv_norm[m * BB + t] = rsqrtf(tot);
    }
    if (m == 0 && t == 0) *loss_slot = 0.f;
}

__global__ __launch_bounds__(256) void dense_write_kernel(
    const float* __restrict__ h_sparse,
    const int*   __restrict__ topk,
    const float* __restrict__ U,
    const float* __restrict__ inv_norm,
    float* __restrict__ out)
{
    const int n = blockIdx.x;
    const int t = threadIdx.x;

    __shared__ float hs[KK * BB];
    __shared__ float ho[KK * BB];
    __shared__ float inv_s[KK * BB];
    __shared__ int   eidx[KK];
    __shared__ float w_s[DD];
    __shared__ float red[256];

    if (t < KK) eidx[t] = topk[n * KK + t];
    __syncthreads();
    if (t < KK * BB) {
        const int k = t / BB, b = t % BB;
        const float h  = h_sparse[(long)n * KK * BB + t];
        const float iv = inv_norm[eidx[k] * BB + b];
        ho[t]    = h;
        inv_s[t] = iv;
        hs[t]    = h * iv;
    }
    __syncthreads();

    #pragma unroll
    for (int dd = 0; dd < 2; ++dd) {
        const int d = t + dd * 256;
        float w = 0.f;
        #pragma unroll
        for (int k = 0; k < KK; ++k) {
            const float4* row = (const float4*)(U + ((long)eidx[k] * DP1 + d) * BB);
            #pragma unroll
            for (int q = 0; q < 4; ++q) {
                const float4 u4 = row[q];
                w += u4.x * hs[k * BB + 4 * q + 0];
                w += u4.y * hs[k * BB + 4 * q + 1];
                w += u4.z * hs[k * BB + 4 * q + 2];
                w += u4.w * hs[k * BB + 4 * q + 3];
            }
        }
        w_s[d] = w;
        out[(long)n * DD + d] = w;
    }
    __syncthreads();

    {
        const int pair = t & 63;
        const int k = pair >> 4, b = pair & 15;
        const int ch = t >> 6;
        const float* Ucol = U + (long)eidx[k] * DP1 * BB + b;
        float p = 0.f;
        #pragma unroll 8
        for (int d = ch * 128; d < ch * 128 + 128; ++d) {
            p += Ucol[(long)d * BB] * w_s[d];
        }
        red[t] = p;
    }
    __syncthreads();

    if (t < 64) {
        const float recon = (red[t] + red[t + 64] + red[t + 128] + red[t + 192]) * inv_s[t];
        const float diff  = recon - ho[t];
        float sq = diff * diff;
        #pragma unroll
        for (int off = 32; off > 0; off >>= 1) sq += __shfl_down(sq, off, 64);
        if (t == 0) {
            atomicAdd(out + (long)NN * DD, sq * (1.0f / ((float)NN * KK * BB)));
        }
    }
}

// ---------------------------------------------------------------------------

extern "C" void kernel_launch(void* const* d_in, const int* in_sizes, int n_in,
                              void* d_out, int out_size, void* d_ws, size_t ws_size,
                              hipStream_t stream) {
    const float* h_sparse = (const float*)d_in[0];
    const int*   topk     = (const int*)d_in[1];
    const float* U        = (const float*)d_in[2];
    float* out = (float*)d_out;

    if (ws_size >= (size_t)WS_NEED) {
        hipMemsetAsync(d_ws, 0, 256, stream);   // expert counters
        hipLaunchKernelGGL(prep_build, dim3(256 + NPAIR / 256), dim3(256), 0, stream,
                           U, topk, d_ws, out + (long)NN * DD);
        // K2: 1024 write-pass blocks (wave-pair split) + 1024 gram blocks
        hipLaunchKernelGGL(pass_writes_mfma, dim3(MM * 16 + 1024), dim3(256), 0, stream,
                           h_sparse, d_ws);
        // K3: 2048 reduce blocks + 1024 loss blocks (loss needs only G from K2)
        hipLaunchKernelGGL(reduce_loss, dim3(NN * DD / 8 / 256 + 1024), dim3(256), 0, stream,
                           h_sparse, topk, d_ws, out);
    } else {
        float* inv_norm = (float*)d_ws;
        hipLaunchKernelGGL(norm_kernel, dim3(MM), dim3(256), 0, stream,
                           U, inv_norm, out + (long)NN * DD);
        hipLaunchKernelGGL(dense_write_kernel, dim3(NN), dim3(256), 0, stream,
                           h_sparse, topk, U, inv_norm, out);
    }
}

// Round 8
// 126.568 us; speedup vs baseline: 1.1380x; 1.0171x over previous
//
#include <hip/hip_runtime.h>

#define DD 512
#define MM 64
#define BB 16
#define NN 8192
#define KK 4
#define DP1 513
#define CAP 1024
#define NPAIR (NN * KK)

// ws byte offsets
#define CNT_B  0                      // 64 int expert counts (256 B)
#define BKT_B  33024                  // 64*1024 ushort pair ids (128 KB)
#define U_B    164096                 // bf16 u[m][d][b], 1 MB
#define UT_B   1212672                // bf16 ut[m][b][d], 1 MB
#define WBF_B  2261248                // bf16 w[n][d], 8 MB
#define PART_B 10649856               // bf16 part[k][n][d], 32 MB
#define WS_NEED 44204288

typedef unsigned int uint;
typedef unsigned short ushort;
typedef __attribute__((ext_vector_type(8))) short short8;
typedef __attribute__((ext_vector_type(4))) float f32x4;

__device__ __forceinline__ ushort f2bf(float f) {
    uint u = __builtin_bit_cast(uint, f);
    uint r = (u + 0x7FFFu + ((u >> 16) & 1u)) >> 16;
    return (ushort)r;
}
__device__ __forceinline__ float bf2f(ushort s) {
    return __builtin_bit_cast(float, (uint)s << 16);
}

// ---------------------------------------------------------------------------
// K1 prep_build: blocks 0-255 = prep (4 blocks/expert, d-slice of 128);
//                blocks 256-383 = counting sort (independent, concurrent).
// cnt[] must be zeroed before this kernel (memset).
// ---------------------------------------------------------------------------
__global__ __launch_bounds__(256) void prep_build(
    const float* __restrict__ U,
    const int*   __restrict__ topk,
    void* __restrict__ ws,
    float* __restrict__ loss_slot)
{
    const int blk = blockIdx.x, t = threadIdx.x;

    if (blk < 256) {
        // ---- prep: expert m, d-slice sl ----
        const int m = blk >> 2, sl = blk & 3;
        const float* Um = U + (long)m * DP1 * BB;

        __shared__ float red[256];
        __shared__ float inv_s[BB];
        __shared__ ushort tr[BB][136];

        float a = 0.f;
        for (int i = t; i < DP1 * BB; i += 256) { float v = Um[i]; a += v * v; }
        red[t] = a;
        __syncthreads();
        if (t < BB) {
            float tot = 0.f;
            #pragma unroll
            for (int j = 0; j < 16; ++j) tot += red[t + 16 * j];
            inv_s[t] = rsqrtf(tot);
        }
        __syncthreads();

        ushort* ub = (ushort*)((char*)ws + U_B) + (long)m * DD * BB + sl * 2048;
        ushort* ut = (ushort*)((char*)ws + UT_B) + (long)m * BB * DD + sl * 128;
        const float* Us = Um + sl * 2048;

        #pragma unroll
        for (int iter = 0; iter < 4; ++iter) {
            const int i = t + iter * 256;      // 0..1023 element pairs
            const int e0 = 2 * i;              // 0..2046
            const int dl = e0 >> 4, b0 = e0 & 15;
            const float2 v = *(const float2*)(Us + e0);
            const ushort bv0 = f2bf(v.x * inv_s[b0]);
            const ushort bv1 = f2bf(v.y * inv_s[b0 + 1]);
            *(uint*)(ub + e0) = (uint)bv0 | ((uint)bv1 << 16);
            tr[b0][dl]     = bv0;
            tr[b0 + 1][dl] = bv1;
        }
        __syncthreads();
        {
            const int b = t >> 4, doff = (t & 15) * 8;
            uint4 val;
            val.x = (uint)tr[b][doff + 0] | ((uint)tr[b][doff + 1] << 16);
            val.y = (uint)tr[b][doff + 2] | ((uint)tr[b][doff + 3] << 16);
            val.z = (uint)tr[b][doff + 4] | ((uint)tr[b][doff + 5] << 16);
            val.w = (uint)tr[b][doff + 6] | ((uint)tr[b][doff + 7] << 16);
            *(uint4*)(ut + (long)b * DD + doff) = val;
        }
    } else {
        // ---- build: counting sort chunk (blk-256) ----
        const int cblk = blk - 256;
        int* cnt = (int*)ws;
        ushort* bkt = (ushort*)((char*)ws + BKT_B);
        __shared__ int lc[MM], lb[MM];
        if (t < MM) lc[t] = 0;
        __syncthreads();
        const int p = cblk * 256 + t;
        const int e = topk[p];
        const int my = atomicAdd(&lc[e], 1);
        __syncthreads();
        if (t < MM) lb[t] = atomicAdd(&cnt[t], lc[t]);
        __syncthreads();
        bkt[e * CAP + lb[e] + my] = (ushort)p;
        if (cblk == 0 && t == 0) *loss_slot = 0.f;
    }
}

// ---------------------------------------------------------------------------
// K2 (MFMA): part[k][n][d] = Un_e * h^T per 16-pair tile (K=16 padded to 32).
// e = blk & 63: all 8 slices of an expert land on one XCD (L2 locality).
// ---------------------------------------------------------------------------
__global__ __launch_bounds__(256) void pass_writes_mfma(
    const float* __restrict__ h_sparse, void* __restrict__ ws)
{
    const int e = blockIdx.x & 63, g = blockIdx.x >> 6;
    const int wave = threadIdx.x >> 6, lane = threadIdx.x & 63;
    const int quad = lane >> 4, l15 = lane & 15;

    const int* cnt = (const int*)ws;
    const ushort* bkt = (const ushort*)((const char*)ws + BKT_B);
    const ushort* Ue = (const ushort*)((const char*)ws + U_B) + (long)e * DD * BB;
    ushort* part = (ushort*)((char*)ws + PART_B);

    const int c  = cnt[e];
    const int lo = (c * g) >> 3;
    const int hi = (c * (g + 1)) >> 3;

    for (int base = lo + wave * 16; base < hi; base += 64) {
        const int pidx = base + l15;
        const bool valid = pidx < hi;
        const int id = valid ? (int)bkt[e * CAP + pidx] : 0;
        const int n = id >> 2, k = id & 3;

        short8 bfrag = (short8)0;
        if (quad < 2 && valid) {
            const float4* hp = (const float4*)(h_sparse + (long)id * BB + quad * 8);
            const float4 h0 = hp[0], h1 = hp[1];
            bfrag[0] = (short)f2bf(h0.x); bfrag[1] = (short)f2bf(h0.y);
            bfrag[2] = (short)f2bf(h0.z); bfrag[3] = (short)f2bf(h0.w);
            bfrag[4] = (short)f2bf(h1.x); bfrag[5] = (short)f2bf(h1.y);
            bfrag[6] = (short)f2bf(h1.z); bfrag[7] = (short)f2bf(h1.w);
        }
        ushort* prow = part + ((long)(k * NN + n) << 9);

        #pragma unroll 2
        for (int dt = 0; dt < 32; dt += 2) {
            short8 a0 = (short8)0, a1 = (short8)0;
            if (quad < 2) {
                a0 = *(const short8*)(Ue + ((long)(dt * 16 + l15) << 4) + quad * 8);
                a1 = *(const short8*)(Ue + ((long)((dt + 1) * 16 + l15) << 4) + quad * 8);
            }
            f32x4 z = {0.f, 0.f, 0.f, 0.f};
            f32x4 c0 = __builtin_amdgcn_mfma_f32_16x16x32_bf16(a0, bfrag, z, 0, 0, 0);
            f32x4 c1 = __builtin_amdgcn_mfma_f32_16x16x32_bf16(a1, bfrag, z, 0, 0, 0);

            uint p0x = (uint)f2bf(c0[0]) | ((uint)f2bf(c0[1]) << 16);
            uint p0y = (uint)f2bf(c0[2]) | ((uint)f2bf(c0[3]) << 16);
            uint p1x = (uint)f2bf(c1[0]) | ((uint)f2bf(c1[1]) << 16);
            uint p1y = (uint)f2bf(c1[2]) | ((uint)f2bf(c1[3]) << 16);
            uint q0x = __shfl_xor((int)p0x, 16, 64);
            uint q0y = __shfl_xor((int)p0y, 16, 64);
            uint q1x = __shfl_xor((int)p1x, 16, 64);
            uint q1y = __shfl_xor((int)p1y, 16, 64);

            if (valid) {
                uint4 st;
                int sdt;
                if ((quad & 1) == 0) { st.x = p0x; st.y = p0y; st.z = q0x; st.w = q0y; sdt = dt; }
                else                 { st.x = q1x; st.y = q1y; st.z = p1x; st.w = p1y; sdt = dt + 1; }
                const int srow = (quad & 2) ? 8 : 0;
                *(uint4*)(prow + sdt * 16 + srow) = st;
            }
        }
    }
}

// ---------------------------------------------------------------------------
// K3: w[n][d] = sum_k part[k][n][d]; write fp32 out (non-temporal: out is
// never re-read, keep L2/L3 hot for part/wbf) + bf16 wbf (coalesced, re-read
// by K4 -> normal stores).
// ---------------------------------------------------------------------------
__global__ __launch_bounds__(256) void reduce_w(
    void* __restrict__ ws, float* __restrict__ out)
{
    const uint4* part4 = (const uint4*)((const char*)ws + PART_B);
    uint4* wbf4 = (uint4*)((char*)ws + WBF_B);
    const int gsz = NN * DD / 8;
    const int gid = blockIdx.x * 256 + threadIdx.x;

    const uint4 v0 = part4[gid];
    const uint4 v1 = part4[(long)gsz + gid];
    const uint4 v2 = part4[2L * gsz + gid];
    const uint4 v3 = part4[3L * gsz + gid];

    float s[8];
    s[0] = bf2f((ushort)v0.x) + bf2f((ushort)v1.x) + bf2f((ushort)v2.x) + bf2f((ushort)v3.x);
    s[1] = bf2f((ushort)(v0.x >> 16)) + bf2f((ushort)(v1.x >> 16)) + bf2f((ushort)(v2.x >> 16)) + bf2f((ushort)(v3.x >> 16));
    s[2] = bf2f((ushort)v0.y) + bf2f((ushort)v1.y) + bf2f((ushort)v2.y) + bf2f((ushort)v3.y);
    s[3] = bf2f((ushort)(v0.y >> 16)) + bf2f((ushort)(v1.y >> 16)) + bf2f((ushort)(v2.y >> 16)) + bf2f((ushort)(v3.y >> 16));
    s[4] = bf2f((ushort)v0.z) + bf2f((ushort)v1.z) + bf2f((ushort)v2.z) + bf2f((ushort)v3.z);
    s[5] = bf2f((ushort)(v0.z >> 16)) + bf2f((ushort)(v1.z >> 16)) + bf2f((ushort)(v2.z >> 16)) + bf2f((ushort)(v3.z >> 16));
    s[6] = bf2f((ushort)v0.w) + bf2f((ushort)v1.w) + bf2f((ushort)v2.w) + bf2f((ushort)v3.w);
    s[7] = bf2f((ushort)(v0.w >> 16)) + bf2f((ushort)(v1.w >> 16)) + bf2f((ushort)(v2.w >> 16)) + bf2f((ushort)(v3.w >> 16));

    f32x4* out4 = (f32x4*)out;
    f32x4 o0 = {s[0], s[1], s[2], s[3]};
    f32x4 o1 = {s[4], s[5], s[6], s[7]};
    __builtin_nontemporal_store(o0, out4 + (long)gid * 2 + 0);
    __builtin_nontemporal_store(o1, out4 + (long)gid * 2 + 1);

    uint4 pk;
    pk.x = (uint)f2bf(s[0]) | ((uint)f2bf(s[1]) << 16);
    pk.y = (uint)f2bf(s[2]) | ((uint)f2bf(s[3]) << 16);
    pk.z = (uint)f2bf(s[4]) | ((uint)f2bf(s[5]) << 16);
    pk.w = (uint)f2bf(s[6]) | ((uint)f2bf(s[7]) << 16);
    wbf4[gid] = pk;
}

// ---------------------------------------------------------------------------
// K4 (MFMA): recon[pair][b] = sum_d w[n][d]*Un[d][b]; loss only.
// e = blk & 63 (XCD locality, same as K2).
// ---------------------------------------------------------------------------
__global__ __launch_bounds__(256) void pass_recon_mfma(
    const float* __restrict__ h_sparse, void* __restrict__ ws,
    float* __restrict__ out)
{
    const int e = blockIdx.x & 63, g = blockIdx.x >> 6;
    const int wave = threadIdx.x >> 6, lane = threadIdx.x & 63;
    const int quad = lane >> 4, l15 = lane & 15;
    const int t = threadIdx.x;

    const int* cnt = (const int*)ws;
    const ushort* bkt = (const ushort*)((const char*)ws + BKT_B);
    const ushort* Ute = (const ushort*)((const char*)ws + UT_B) + (long)e * BB * DD;
    const ushort* wbf = (const ushort*)((const char*)ws + WBF_B);

    __shared__ float loss_blk;
    if (t == 0) loss_blk = 0.f;
    __syncthreads();

    const int c  = cnt[e];
    const int lo = (c * g) >> 3;
    const int hi = (c * (g + 1)) >> 3;

    float lsum = 0.f;
    for (int base = lo + wave * 16; base < hi; base += 64) {
        const int pidx = base + l15;
        const bool valid = pidx < hi;
        const int id = valid ? (int)bkt[e * CAP + pidx] : 0;
        const int n = id >> 2;
        const ushort* wrow = wbf + ((long)n << 9);

        f32x4 acc = {0.f, 0.f, 0.f, 0.f};
        #pragma unroll 4
        for (int kk = 0; kk < 16; ++kk) {
            const int doff = kk * 32 + quad * 8;
            const short8 afrag = *(const short8*)(wrow + doff);
            const short8 bfrag = *(const short8*)(Ute + (long)l15 * DD + doff);
            acc = __builtin_amdgcn_mfma_f32_16x16x32_bf16(afrag, bfrag, acc, 0, 0, 0);
        }
        #pragma unroll
        for (int r = 0; r < 4; ++r) {
            const int pr = base + quad * 4 + r;
            if (pr < hi) {
                const int id2 = (int)bkt[e * CAP + pr];
                const float h = h_sparse[(long)id2 * BB + l15];
                const float d = acc[r] - h;
                lsum += d * d;
            }
        }
    }
    #pragma unroll
    for (int off = 32; off > 0; off >>= 1) lsum += __shfl_xor(lsum, off, 64);
    if (lane == 0 && lsum != 0.f) atomicAdd(&loss_blk, lsum);
    __syncthreads();
    if (t == 0 && loss_blk != 0.f)
        atomicAdd(out + (long)NN * DD, loss_blk * (1.0f / ((float)NN * KK * BB)));
}

// ---------------------------------------------------------------------------
// Fallback (round-1 proven): tiny workspace
// ---------------------------------------------------------------------------
__global__ __launch_bounds__(256) void norm_kernel(
    const float* __restrict__ U, float* __restrict__ inv_norm,
    float* __restrict__ loss_slot)
{
    const int m = blockIdx.x;
    const int t = threadIdx.x;
    const float* Um = U + (long)m * DP1 * BB;
    float acc = 0.f;
    for (int idx = t; idx < DP1 * BB; idx += 256) {
        float v = Um[idx];
        acc += v * v;
    }
    __shared__ float s[256];
    s[t] = acc;
    __syncthreads();
    if (t < BB) {
        float tot = 0.f;
        #pragma unroll
        for (int j = 0; j < 16; ++j) tot += s[t + 16 * j];
        inv_norm[m * BB + t] = rsqrtf(tot);
    }
    if (m == 0 && t == 0) *loss_slot = 0.f;
}

__global__ __launch_bounds__(256) void dense_write_kernel(
    const float* __restrict__ h_sparse,
    const int*   __restrict__ topk,
    const float* __restrict__ U,
    const float* __restrict__ inv_norm,
    float* __restrict__ out)
{
    const int n = blockIdx.x;
    const int t = threadIdx.x;

    __shared__ float hs[KK * BB];
    __shared__ float ho[KK * BB];
    __shared__ float inv_s[KK * BB];
    __shared__ int   eidx[KK];
    __shared__ float w_s[DD];
    __shared__ float red[256];

    if (t < KK) eidx[t] = topk[n * KK + t];
    __syncthreads();
    if (t < KK * BB) {
        const int k = t / BB, b = t % BB;
        const float h  = h_sparse[(long)n * KK * BB + t];
        const float iv = inv_norm[eidx[k] * BB + b];
        ho[t]    = h;
        inv_s[t] = iv;
        hs[t]    = h * iv;
    }
    __syncthreads();

    #pragma unroll
    for (int dd = 0; dd < 2; ++dd) {
        const int d = t + dd * 256;
        float w = 0.f;
        #pragma unroll
        for (int k = 0; k < KK; ++k) {
            const float4* row = (const float4*)(U + ((long)eidx[k] * DP1 + d) * BB);
            #pragma unroll
            for (int q = 0; q < 4; ++q) {
                const float4 u4 = row[q];
                w += u4.x * hs[k * BB + 4 * q + 0];
                w += u4.y * hs[k * BB + 4 * q + 1];
                w += u4.z * hs[k * BB + 4 * q + 2];
                w += u4.w * hs[k * BB + 4 * q + 3];
            }
        }
        w_s[d] = w;
        out[(long)n * DD + d] = w;
    }
    __syncthreads();

    {
        const int pair = t & 63;
        const int k = pair >> 4, b = pair & 15;
        const int ch = t >> 6;
        const float* Ucol = U + (long)eidx[k] * DP1 * BB + b;
        float p = 0.f;
        #pragma unroll 8
        for (int d = ch * 128; d < ch * 128 + 128; ++d) {
            p += Ucol[(long)d * BB] * w_s[d];
        }
        red[t] = p;
    }
    __syncthreads();

    if (t < 64) {
        const float recon = (red[t] + red[t + 64] + red[t + 128] + red[t + 192]) * inv_s[t];
        const float diff  = recon - ho[t];
        float sq = diff * diff;
        #pragma unroll
        for (int off = 32; off > 0; off >>= 1) sq += __shfl_down(sq, off, 64);
        if (t == 0) {
            atomicAdd(out + (long)NN * DD, sq * (1.0f / ((float)NN * KK * BB)));
        }
    }
}

// ---------------------------------------------------------------------------

extern "C" void kernel_launch(void* const* d_in, const int* in_sizes, int n_in,
                              void* d_out, int out_size, void* d_ws, size_t ws_size,
                              hipStream_t stream) {
    const float* h_sparse = (const float*)d_in[0];
    const int*   topk     = (const int*)d_in[1];
    const float* U        = (const float*)d_in[2];
    float* out = (float*)d_out;

    if (ws_size >= (size_t)WS_NEED) {
        hipMemsetAsync(d_ws, 0, 256, stream);   // expert counters
        hipLaunchKernelGGL(prep_build, dim3(256 + NPAIR / 256), dim3(256), 0, stream,
                           U, topk, d_ws, out + (long)NN * DD);
        hipLaunchKernelGGL(pass_writes_mfma, dim3(MM * 8), dim3(256), 0, stream,
                           h_sparse, d_ws);
        hipLaunchKernelGGL(reduce_w, dim3(NN * DD / 8 / 256), dim3(256), 0, stream,
                           d_ws, out);
        hipLaunchKernelGGL(pass_recon_mfma, dim3(MM * 8), dim3(256), 0, stream,
                           h_sparse, d_ws, out);
    } else {
        float* inv_norm = (float*)d_ws;
        hipLaunchKernelGGL(norm_kernel, dim3(MM), dim3(256), 0, stream,
                           U, inv_norm, out + (long)NN * DD);
        hipLaunchKernelGGL(dense_write_kernel, dim3(NN), dim3(256), 0, stream,
                           h_sparse, topk, U, inv_norm, out);
    }
}